// Round 17
// baseline (139.256 us; speedup 1.0000x reference)
//
#include <hip/hip_runtime.h>
#include <hip/hip_bf16.h>

typedef __attribute__((ext_vector_type(8))) __bf16 bf16x8;
typedef __attribute__((ext_vector_type(4))) __bf16 bf16x4;
typedef __attribute__((ext_vector_type(4))) float  f32x4;

// ---------------------------------------------------------------------------
// async global->LDS, 16B per lane. LDS dest must be wave-uniform base.
__device__ __forceinline__ void gl_lds16(const __bf16* g, __bf16* l) {
  __builtin_amdgcn_global_load_lds(
      (const __attribute__((address_space(1))) void*)g,
      (__attribute__((address_space(3))) void*)l,
      16, 0, 0);
}

// ---------------------------------------------------------------------------
// Merged prep: role-switched by block range.
__global__ __launch_bounds__(256) void prep_kernel(
    const float* __restrict__ x, const float* __restrict__ gen,
    const float* __restrict__ Wq, const float* __restrict__ Wv, const float* __restrict__ Wc,
    __bf16* __restrict__ xb, __bf16* __restrict__ genT,
    __bf16* __restrict__ wqT, __bf16* __restrict__ wvT, __bf16* __restrict__ wcb,
    float* __restrict__ gp) {
  __shared__ float S[64][65];
  const int blk = blockIdx.x, tid = threadIdx.x;

  if (blk < 128) { // transposes
    const float* in = (blk < 64) ? Wq : Wv;
    __bf16* out = (blk < 64) ? wqT : wvT;
    int t = blk & 63;
    int tx = tid & 63, ty = tid >> 6;
    int d0 = (t >> 3) * 64, e0 = (t & 7) * 64;
#pragma unroll
    for (int i = 0; i < 16; ++i) {
      int di = i * 4 + ty;
      S[di][tx] = in[(long)(d0 + di) * 512 + e0 + tx];
    }
    __syncthreads();
#pragma unroll
    for (int i = 0; i < 16; ++i) {
      int ei = i * 4 + ty;
      out[(long)(e0 + ei) * 512 + d0 + tx] = (__bf16)S[tx][ei];
    }
  } else if (blk < 384) { // Wc f2bf
    int i = (blk - 128) * 256 + tid;
    float4 v = ((const float4*)Wc)[i];
    bf16x4 o;
    o[0] = (__bf16)v.x; o[1] = (__bf16)v.y; o[2] = (__bf16)v.z; o[3] = (__bf16)v.w;
    *(bf16x4*)(wcb + 4L * i) = o;
  } else if (blk < 2432) { // genT
    int i = blk - 384;
    for (int d = tid; d < 512; d += 256) {
      float v = (i < 2047) ? gen[(long)d * 2047 + i] : 0.f;
      genT[(long)i * 512 + d] = (__bf16)v;
    }
  } else if (blk < 10624) { // x f2bf
    int i = (blk - 2432) * 256 + tid;
    float4 v = ((const float4*)x)[i];
    bf16x4 o;
    o[0] = (__bf16)v.x; o[1] = (__bf16)v.y; o[2] = (__bf16)v.z; o[3] = (__bf16)v.w;
    *(bf16x4*)(xb + 4L * i) = o;
  } else { // g2t partials
    int t = blk - 10624;       // 0..503
    int i = t % 63, c = t / 63;
    int d0 = c * 64, k = tid;
    float a0 = 0.f, a1 = 0.f;
#pragma unroll 8
    for (int u = 0; u < 64; ++u) {
      int d = d0 + u;
      float g = gen[(long)d * 2047 + 992 + i];
      a0 += Wq[(long)d * 512 + k] * g;
      a1 += Wq[(long)d * 512 + k + 256] * g;
    }
    long o = ((long)c * 63 + i) * 512;
    gp[o + k] = a0;
    gp[o + k + 256] = a1;
  }
}

// ---------------------------------------------------------------------------
// Shared 128x128 3-deep counted-vmcnt GEMM core (BK=32, 4 waves, C=A@B^T),
// LDS XOR-swizzled. 4 loads/stage -> steady wait vmcnt(8), tail 4/0.
__device__ __forceinline__ void gemm128_body(
    const __bf16* __restrict__ Ab, const __bf16* __restrict__ Bb,
    __bf16 (*As)[128 * 32], __bf16 (*Bs)[128 * 32],
    int m0, int n0, int K, int nt, f32x4 (&acc)[4][4]) {
  const int tid = threadIdx.x;
  const int w = tid >> 6, l = tid & 63;
  const int srow = w * 16 + (l >> 2);
  const int scol = (((l & 3) ^ ((l >> 3) & 3))) * 8;     // swizzled source chunk
  const int wr = (w >> 1) * 64, wc = (w & 1) * 64;
  const int fr = l & 15;
  const int cp = (((l >> 4) ^ ((fr >> 1) & 3))) << 3;    // swizzled read chunk (elems)

  auto STAGE = [&](int t, int p) {
    const int k0 = t << 5;
    gl_lds16(Ab + (long)(m0 + srow) * K + (k0 + scol),      &As[p][(w * 16) * 32]);
    gl_lds16(Ab + (long)(m0 + 64 + srow) * K + (k0 + scol), &As[p][(64 + w * 16) * 32]);
    gl_lds16(Bb + (long)(n0 + srow) * K + (k0 + scol),      &Bs[p][(w * 16) * 32]);
    gl_lds16(Bb + (long)(n0 + 64 + srow) * K + (k0 + scol), &Bs[p][(64 + w * 16) * 32]);
  };
  STAGE(0, 0);
  if (nt > 1) STAGE(1, 1);
  if (nt > 2) STAGE(2, 2);
  int p = 0;
  for (int t = 0; t < nt; ++t) {
    const int ahead = nt - 1 - t;
    if (ahead >= 2)      asm volatile("s_waitcnt vmcnt(8)\ns_barrier" ::: "memory");
    else if (ahead == 1) asm volatile("s_waitcnt vmcnt(4)\ns_barrier" ::: "memory");
    else                 asm volatile("s_waitcnt vmcnt(0)\ns_barrier" ::: "memory");
    bf16x8 af[4], bg[4];
#pragma unroll
    for (int i = 0; i < 4; ++i) af[i] = *(const bf16x8*)&As[p][(wr + i * 16 + fr) * 32 + cp];
#pragma unroll
    for (int j = 0; j < 4; ++j) bg[j] = *(const bf16x8*)&Bs[p][(wc + j * 16 + fr) * 32 + cp];
    asm volatile("s_waitcnt lgkmcnt(0)\ns_barrier" ::: "memory");
    if (t + 3 < nt) STAGE(t + 3, p);
#pragma unroll
    for (int i = 0; i < 4; ++i)
#pragma unroll
      for (int j = 0; j < 4; ++j)
        acc[i][j] = __builtin_amdgcn_mfma_f32_16x16x32_bf16(af[i], bg[j], acc[i][j], 0, 0, 0);
    p = (p == 2) ? 0 : p + 1;
  }
}

// ---------------------------------------------------------------------------
// Merged weight-folding GEMMs + g2t reduce in one dispatch (206 blocks):
//   blk [0,16):    Pmat = wcb @ wvT^T   (512x512, grid 4x4)
//   blk [16,80):   Bg   = genT @ wqT^T  (2048x512, grid 16x4)
//   blk [80,206):  g2t reduce (8 partial slabs -> f32)
__global__ __launch_bounds__(256) void gemm_fold(
    const __bf16* __restrict__ A1, const __bf16* __restrict__ B1, __bf16* __restrict__ C1,
    const __bf16* __restrict__ A2, const __bf16* __restrict__ B2, __bf16* __restrict__ C2,
    const float* __restrict__ gp, float* __restrict__ g2t) {
  __shared__ __bf16 As[3][128 * 32];
  __shared__ __bf16 Bs[3][128 * 32];
  const int b = blockIdx.x;
  if (b >= 80) { // g2t reduce
    int idx = (b - 80) * 256 + threadIdx.x;
    if (idx >= 63 * 512) return;
    float s = 0.f;
#pragma unroll
    for (int c = 0; c < 8; ++c) s += gp[(long)c * 63 * 512 + idx];
    g2t[idx] = s;
    return;
  }
  const __bf16 *Ab, *Bb; __bf16* C; int m0, n0;
  if (b < 16) { Ab = A1; Bb = B1; C = C1; m0 = (b >> 2) * 128; n0 = (b & 3) * 128; }
  else { int t = b - 16; Ab = A2; Bb = B2; C = C2; m0 = (t >> 2) * 128; n0 = (t & 3) * 128; }

  f32x4 acc[4][4] = {};
  gemm128_body(Ab, Bb, As, Bs, m0, n0, 512, 16, acc);

  const int l = threadIdx.x & 63, w = threadIdx.x >> 6;
  const int rbase = m0 + (w >> 1) * 64 + ((l >> 4) << 2);
  const int cbase = n0 + (w & 1) * 64 + (l & 15);
#pragma unroll
  for (int i = 0; i < 4; ++i)
#pragma unroll
    for (int r = 0; r < 4; ++r) {
      long row = rbase + i * 16 + r;
#pragma unroll
      for (int j = 0; j < 4; ++j) C[row * 512 + cbase + j * 16] = (__bf16)acc[i][j][r];
    }
}

// ---------------------------------------------------------------------------
// Final GEMM: OUT[b] = normalize(Wrelu[b]) @ vT[b]^T -> f32 d_out.
// TRIL: K-loop ends at m0+128. 1D XCD-chunked grid (512 = 8 x 64).
__global__ __launch_bounds__(256) void gemm_out(
    const __bf16* __restrict__ A, const __bf16* __restrict__ B, float* __restrict__ Cv,
    const float* __restrict__ aux) {
  __shared__ __bf16 As[3][128 * 32];
  __shared__ __bf16 Bs[3][128 * 32];
  int bid = blockIdx.x;
  int swz = (bid & 7) * 64 + (bid >> 3);
  int xn = swz & 3, tt = swz >> 2;
  int yn = tt & 7, bz = tt >> 3;
  const int m0 = yn * 128, n0 = xn * 128;
  const int K = 1024;
  const __bf16* Ab = A + (long)bz * 1024 * 1024;
  const __bf16* Bb = B + (long)bz * 512 * 1024;
  const int nt = (m0 + 128) >> 5;   // min(K, m0+128)/32

  f32x4 acc[4][4] = {};
  gemm128_body(Ab, Bb, As, Bs, m0, n0, K, nt, acc);

  const int l = threadIdx.x & 63, w = threadIdx.x >> 6;
  const int rbase = m0 + (w >> 1) * 64 + ((l >> 4) << 2);
  const int cbase = n0 + (w & 1) * 64 + (l & 15);
  float* C = Cv + (long)bz * 512 * 1024;
  const float* ax = aux + bz * 1024;
#pragma unroll
  for (int i = 0; i < 4; ++i)
#pragma unroll
    for (int r = 0; r < 4; ++r) {
      long row = rbase + i * 16 + r;
      float sc = 1.f / (ax[row] + 1e-8f);
#pragma unroll
      for (int j = 0; j < 4; ++j) C[row * 512 + cbase + j * 16] = acc[i][j][r] * sc;
    }
}

// ---------------------------------------------------------------------------
// Merged x-GEMM, 8-PHASE template (m201 port): BM=BN=256, BK=64, 512 thr,
// 8 waves (2M x 4N, per-wave C 128x64). LDS 128 KiB (2 dbuf x 256x64 x A,B).
// Per K-tile: bg hoisted to regs at phase 0; af per phase (i-pair); 16 MFMA
// per phase with setprio. Counted vmcnt(6) ONLY at phase 0 of each K-tile
// (FIFO-derived); vmcnt(0) only at the last K-tile. Stage slots derived from
// buffer-free times (see schedule below); every stage lands after its
// buffer's last reader passed a barrier.
//   stage schedule per iter J (computes kt=2J in d0 phases 0-3, 2J+1 in d1
//   phases 4-7): ph0: A(2J+1)h0->d1 | ph1: A(2J+1)h1->d1, B(2J+2)h0->d0 |
//   ph2: B(2J+2)h1->d0 | ph4: A(2J+2)h0->d0 | ph5: A(2J+2)h1->d0,
//   B(2J+3)h0->d1 | ph6: B(2J+3)h1->d1.   (forward stages guarded J<3)
// Band at BN=256: 5 n-tiles/m-tile (start 3-(y&3)) + 2 vT tiles.
// Grid 448 = 8 x 56 (bijective XCD chunking).
__global__ __launch_bounds__(512) void gemm_x(
    const __bf16* __restrict__ A, const __bf16* __restrict__ Bg,
    const __bf16* __restrict__ Pm, __bf16* __restrict__ S, __bf16* __restrict__ vT) {
  __shared__ __bf16 Al[2][256 * 64];
  __shared__ __bf16 Bl[2][256 * 64];
  const int tid = threadIdx.x;
  const int w = tid >> 6, l = tid & 63;

  int wgid = blockIdx.x;
  int swz = (wgid & 7) * 56 + (wgid >> 3);
  int y = swz / 7, xt = swz - y * 7;
  const bool band = (xt < 5);
  const int m0 = y * 256;
  const int n0 = band ? (3 - (y & 3) + xt) * 256 : (xt - 5) * 256;
  const __bf16* Bb = band ? Bg : Pm;
  const int K = 512;

  const int wm = w >> 2, wn = w & 3;     // 2M x 4N wave grid
  const int fr = l & 15, fq = l >> 4;
  const int srow = tid >> 3;             // staging: row-in-64
  const int scol = ((tid & 7) ^ (srow & 7)) * 8;  // swizzled source col-chunk
  const int rx = fr & 7;                 // read-side xor

  const __bf16* Abase = A + (long)m0 * K;
  const __bf16* Bbase = Bb + (long)n0 * K;

  f32x4 acc[8][4] = {};

  auto STAGE = [&](int kt, int h, int d, bool isB) {
    const __bf16* src = isB ? Bbase : Abase;
    __bf16* dst = isB ? &Bl[d][0] : &Al[d][0];
    const int kc = kt * 64 + scol;
#pragma unroll
    for (int q = 0; q < 2; ++q) {
      const int r0 = h * 128 + q * 64;
      gl_lds16(src + (long)(r0 + srow) * K + kc, dst + (r0 + w * 8) * 64);
    }
  };

  // prologue: B(0)->d0, A(0)->d0, B(1)->d1  (12 loads, exact FIFO order)
  STAGE(0, 0, 0, true);  STAGE(0, 1, 0, true);
  STAGE(0, 0, 0, false); STAGE(0, 1, 0, false);
  STAGE(1, 0, 1, true);  STAGE(1, 1, 1, true);

  for (int J = 0; J < 4; ++J) {
    const bool more = (J < 3);
#pragma unroll
    for (int ktl = 0; ktl < 2; ++ktl) {
      const int d = ktl;                 // compile-time dbuf
      bf16x8 bg[4][2];
#pragma unroll
      for (int p = 0; p < 4; ++p) {
        // --- staging (issued before the wait so FIFO counts match) ---
        if (ktl == 0) {
          if (p == 0) STAGE(2 * J + 1, 0, 1, false);
          else if (p == 1) { STAGE(2 * J + 1, 1, 1, false);
                             if (more) STAGE(2 * J + 2, 0, 0, true); }
          else if (p == 2) { if (more) STAGE(2 * J + 2, 1, 0, true); }
        } else {
          if (p == 0) { if (more) STAGE(2 * J + 2, 0, 0, false); }
          else if (p == 1) { if (more) { STAGE(2 * J + 2, 1, 0, false);
                                         STAGE(2 * J + 3, 0, 1, true); } }
          else if (p == 2) { if (more) STAGE(2 * J + 3, 1, 1, true); }
        }
        // --- wait + entry barrier (K-tile boundary only) ---
        if (p == 0) {
          if (ktl == 1 && J == 3) asm volatile("s_waitcnt vmcnt(0)\ns_barrier" ::: "memory");
          else                    asm volatile("s_waitcnt vmcnt(6)\ns_barrier" ::: "memory");
        }
        // --- ds_reads ---
        if (p == 0) {
#pragma unroll
          for (int j = 0; j < 4; ++j)
#pragma unroll
            for (int ks = 0; ks < 2; ++ks) {
              const int rho = (wn >> 1) * 128 + (wn & 1) * 64 + j * 16 + fr;
              bg[j][ks] = *(const bf16x8*)&Bl[d][rho * 64 + (((ks << 2) + fq) ^ rx) * 8];
            }
        }
        bf16x8 af[2][2];
#pragma unroll
        for (int u = 0; u < 2; ++u)
#pragma unroll
          for (int ks = 0; ks < 2; ++ks) {
            const int rho = wm * 128 + (2 * p + u) * 16 + fr;
            af[u][ks] = *(const bf16x8*)&Al[d][rho * 64 + (((ks << 2) + fq) ^ rx) * 8];
          }
        // reads must be RETURNED before this wave passes the exit barrier
        asm volatile("s_waitcnt lgkmcnt(0)" ::: "memory");
        __builtin_amdgcn_s_setprio(1);
#pragma unroll
        for (int u = 0; u < 2; ++u)
#pragma unroll
          for (int j = 0; j < 4; ++j)
#pragma unroll
            for (int ks = 0; ks < 2; ++ks)
              acc[2 * p + u][j] = __builtin_amdgcn_mfma_f32_16x16x32_bf16(
                  af[u][ks], bg[j][ks], acc[2 * p + u][j], 0, 0, 0);
        __builtin_amdgcn_s_setprio(0);
        asm volatile("s_barrier" ::: "memory");
      }
    }
  }

  const int rbase = m0 + wm * 128 + (fq << 2);
  const int cbase = n0 + wn * 64 + fr;

  if (band) {
#pragma unroll
    for (int i = 0; i < 8; ++i)
#pragma unroll
      for (int r = 0; r < 4; ++r) {
        int row = rbase + i * 16 + r;
        int lloc = row & 1023;
#pragma unroll
        for (int j = 0; j < 4; ++j) {
          int jj = cbase + j * 16 - 1023 + lloc;
          if ((unsigned)jj < 1024u)
            S[(long)row * 1024 + jj] = (__bf16)acc[i][j][r];
        }
      }
  } else {
#pragma unroll
    for (int i = 0; i < 8; ++i) {
      int gm = rbase + i * 16;
      int bt = gm >> 10, lloc = gm & 1023;
#pragma unroll
      for (int j = 0; j < 4; ++j) {
        bf16x4 pk;
        pk[0] = (__bf16)acc[i][j][0]; pk[1] = (__bf16)acc[i][j][1];
        pk[2] = (__bf16)acc[i][j][2]; pk[3] = (__bf16)acc[i][j][3];
        *(bf16x4*)&vT[((long)bt * 512 + cbase + j * 16) * 1024 + lloc] = pk;
      }
    }
  }
}

// ---------------------------------------------------------------------------
// Cumsum over l of S[b,l,j], 64 chunks of 16 rows, bf16x8-vectorized.
// Blocks with c<8 also zero the rowsum segment (replaces the memset dispatch).
__global__ __launch_bounds__(128) void chunk_sums(const __bf16* __restrict__ S,
                                                  float* __restrict__ csum,
                                                  float* __restrict__ rowsum) {
  int j0 = threadIdx.x * 8;
  int c = blockIdx.x, b = blockIdx.y;
  if (c < 8) rowsum[b * 1024 + c * 128 + threadIdx.x] = 0.f;
  const __bf16* Sb = S + (long)b * 1024 * 1024;
  float a[8] = {};
  int l0 = c * 16;
  for (int l = l0; l < l0 + 16; ++l) {
    bf16x8 v = *(const bf16x8*)&Sb[(long)l * 1024 + j0];
#pragma unroll
    for (int k = 0; k < 8; ++k) a[k] += (float)v[k];
  }
  long o = ((long)(b * 64 + c) << 10) + j0;
#pragma unroll
  for (int k = 0; k < 8; ++k) csum[o + k] = a[k];
}

// ---------------------------------------------------------------------------
// Merged: blocks [0,64) = exclusive scan (parallel-load, register array);
//         blocks [64,4160) = small_dots (exact f32 path, rows l<32 -> Sbuf).
__global__ __launch_bounds__(256) void scan_dots(
    float* __restrict__ csum,
    const float* __restrict__ x, const float* __restrict__ g2t, float* __restrict__ Sg) {
  const int blk = blockIdx.x, tid = threadIdx.x;
  if (blk < 64) {
    int idx = blk * 256 + tid; // 0..16383
    int b = idx >> 10, j = idx & 1023;
    long base = ((long)b * 64 << 10) + j;
    float v[64];
#pragma unroll
    for (int c = 0; c < 64; ++c) v[c] = csum[base + ((long)c << 10)];
    float s = 0.f;
#pragma unroll
    for (int c = 0; c < 64; ++c) { csum[base + ((long)c << 10)] = s; s += v[c]; }
  } else {
    int gid = (blk - 64) * 4 + (tid >> 6); // 0..16383
    int lane = tid & 63;
    int b = gid >> 10, rem = gid & 1023, m = rem >> 5, j = rem & 31;
    const float4* xr = (const float4*)(x + ((long)b * 1024 + m) * 512);
    const float4* gr = (const float4*)(g2t + (long)(31 - m + j) * 512);
    float4 a0 = xr[lane * 2], a1 = xr[lane * 2 + 1];
    float4 c0 = gr[lane * 2], c1 = gr[lane * 2 + 1];
    float s = a0.x * c0.x + a0.y * c0.y + a0.z * c0.z + a0.w * c0.w
            + a1.x * c1.x + a1.y * c1.y + a1.z * c1.z + a1.w * c1.w;
#pragma unroll
    for (int off = 32; off; off >>= 1) s += __shfl_down(s, off);
    if (lane == 0) Sg[gid] = s;
  }
}

// ---------------------------------------------------------------------------
// Walk chunk with offset, relu+tril, bf16x8 store (skip dead tiles), fused
// rowsum atomics. EXACT PATH: blocks c<2, threads j0<32 use Sbuf (f32 dots)
// instead of Smat -> rows l<32 get exact weights AND exact rowsum.
__global__ __launch_bounds__(128) void cumsum_relu(const __bf16* __restrict__ S,
                                                   const float* __restrict__ csum,
                                                   const float* __restrict__ Sx,
                                                   __bf16* __restrict__ wrelu,
                                                   float* __restrict__ rowsum) {
  int j0 = threadIdx.x * 8;
  int c = blockIdx.x, b = blockIdx.y;
  const bool exact = (c < 2) && (j0 < 32);
  float run[8];
  if (exact) {
#pragma unroll
    for (int k = 0; k < 8; ++k) run[k] = 0.f;
    for (int m = 0; m < c * 16; ++m)
#pragma unroll
      for (int k = 0; k < 8; ++k) run[k] += Sx[b * 1024 + m * 32 + j0 + k];
  } else {
    long co = ((long)(b * 64 + c) << 10) + j0;
#pragma unroll
    for (int k = 0; k < 8; ++k) run[k] = csum[co + k];
  }
  const __bf16* Sb = S + (long)b * 1024 * 1024;
  __bf16* wr = wrelu + (long)b * 1024 * 1024;
  int l0 = c * 16;
  for (int l = l0; l < l0 + 16; ++l) {
    bf16x8 o;
    float rs = 0.f;
    if (exact) {
#pragma unroll
      for (int k = 0; k < 8; ++k) {
        run[k] += Sx[b * 1024 + l * 32 + j0 + k];
        float val = (j0 + k <= l) ? fmaxf(run[k], 0.f) : 0.f;
        o[k] = (__bf16)val;
        rs += val;
      }
    } else {
      bf16x8 v = *(const bf16x8*)&Sb[(long)l * 1024 + j0];
#pragma unroll
      for (int k = 0; k < 8; ++k) {
        run[k] += (float)v[k];
        float val = (j0 + k <= l) ? fmaxf(run[k], 0.f) : 0.f;
        o[k] = (__bf16)val;
        rs += val;
      }
    }
    if (j0 < (((l >> 7) + 1) << 7))
      *(bf16x8*)&wr[(long)l * 1024 + j0] = o;
#pragma unroll
    for (int off = 32; off; off >>= 1) rs += __shfl_down(rs, off);
    if ((threadIdx.x & 63) == 0 && rs != 0.f) atomicAdd(&rowsum[b * 1024 + l], rs);
  }
}

// ---------------------------------------------------------------------------
extern "C" void kernel_launch(void* const* d_in, const int* in_sizes, int n_in,
                              void* d_out, int out_size, void* d_ws, size_t ws_size,
                              hipStream_t stream) {
  const float* x   = (const float*)d_in[0];
  const float* gen = (const float*)d_in[1];
  const float* Wq  = (const float*)d_in[2];
  const float* Wv  = (const float*)d_in[3];
  const float* Wc  = (const float*)d_in[4];

  char* ws = (char*)d_ws;
  __bf16* xb    = (__bf16*)(ws + 0L);
  __bf16* vT    = (__bf16*)(ws + 33554432L);
  __bf16* Smat  = (__bf16*)(ws + 67108864L);   // gathered scores, 32 MiB
  __bf16* wrelu = (__bf16*)(ws + 134217728L);
  __bf16* genT  = (__bf16*)(ws + 167772160L);
  __bf16* wqT   = (__bf16*)(ws + 169869312L);
  __bf16* wvT   = (__bf16*)(ws + 170393600L);
  __bf16* wcb   = (__bf16*)(ws + 170917888L);
  float*  g2t   = (float*)(ws + 171442176L);
  // overlays in the free region at 16 MiB:
  float*  csum  = (float*)(ws + 16777216L);            // 4 MiB (16*64*1024 f32)
  float*  rsum  = (float*)(ws + 16777216L + 4194304L); // 64 KiB
  float*  Sbuf  = (float*)(ws + 16777216L + 4259840L); // 64 KiB
  // overlays in the free region at 48 MiB:
  __bf16* Pmat  = (__bf16*)(ws + 50331648L);           // 512x512 bf16 (Wc@Wv)
  __bf16* Bg    = (__bf16*)(ws + 51380224L);           // 2048x512 bf16 (gen^T@Wq^T)
  float*  gp    = (float*)(ws + 58720256L);            // 1 MiB g2t partials

  // merged prep: transposes + f2bf (Wc, x) + genT + g2t partials
  prep_kernel<<<11128, 256, 0, stream>>>(x, gen, Wq, Wv, Wc, xb, genT, wqT, wvT, wcb, gp);

  // merged weight folding (Pmat, Bg) + g2t reduce, one dispatch
  gemm_fold<<<206, 256, 0, stream>>>(wcb, wvT, Pmat, genT, wqT, Bg, gp, g2t);

  // merged: gathered S = band(x@Bg^T) ; vT = (x@P^T)^T   (256x256, 8-phase)
  gemm_x<<<448, 512, 0, stream>>>(xb, Bg, Pmat, Smat, vT);

  // cumsum + relu/tril + fused rowsum (64 chunks of 16; chunk_sums zeros rsum)
  chunk_sums<<<dim3(64, 16), 128, 0, stream>>>(Smat, csum, rsum);
  scan_dots<<<4160, 256, 0, stream>>>(csum, x, g2t, Sbuf);
  cumsum_relu<<<dim3(64, 16), 128, 0, stream>>>(Smat, csum, Sbuf, wrelu, rsum);

  // OUT = normalize(Wrelu) @ vc  (batched, triangular) -> f32 d_out directly
  gemm_out<<<512, 256, 0, stream>>>(wrelu, vT, (float*)d_out, rsum);
}

// Round 18
// 137.652 us; speedup vs baseline: 1.0116x; 1.0116x over previous
//
#include <hip/hip_runtime.h>
#include <hip/hip_bf16.h>

typedef __attribute__((ext_vector_type(8))) __bf16 bf16x8;
typedef __attribute__((ext_vector_type(4))) __bf16 bf16x4;
typedef __attribute__((ext_vector_type(4))) float  f32x4;

// ---------------------------------------------------------------------------
// async global->LDS, 16B per lane. LDS dest must be wave-uniform base.
__device__ __forceinline__ void gl_lds16(const __bf16* g, __bf16* l) {
  __builtin_amdgcn_global_load_lds(
      (const __attribute__((address_space(1))) void*)g,
      (__attribute__((address_space(3))) void*)l,
      16, 0, 0);
}

// LDS XOR-swizzle (T2 via rule #21): conflicts measured 0 (r12). Pipeline:
// 3 buffers, depth-2 counted vmcnt, two barriers per K-step — measured best
// across 5 structural A/Bs (tile up, depth up, swizzle, 1-barrier, 8-phase).

// ---------------------------------------------------------------------------
// Merged prep: role-switched by block range.
__global__ __launch_bounds__(256) void prep_kernel(
    const float* __restrict__ x, const float* __restrict__ gen,
    const float* __restrict__ Wq, const float* __restrict__ Wv, const float* __restrict__ Wc,
    __bf16* __restrict__ xb, __bf16* __restrict__ genT,
    __bf16* __restrict__ wqT, __bf16* __restrict__ wvT, __bf16* __restrict__ wcb,
    float* __restrict__ gp) {
  __shared__ float S[64][65];
  const int blk = blockIdx.x, tid = threadIdx.x;

  if (blk < 128) { // transposes
    const float* in = (blk < 64) ? Wq : Wv;
    __bf16* out = (blk < 64) ? wqT : wvT;
    int t = blk & 63;
    int tx = tid & 63, ty = tid >> 6;
    int d0 = (t >> 3) * 64, e0 = (t & 7) * 64;
#pragma unroll
    for (int i = 0; i < 16; ++i) {
      int di = i * 4 + ty;
      S[di][tx] = in[(long)(d0 + di) * 512 + e0 + tx];
    }
    __syncthreads();
#pragma unroll
    for (int i = 0; i < 16; ++i) {
      int ei = i * 4 + ty;
      out[(long)(e0 + ei) * 512 + d0 + tx] = (__bf16)S[tx][ei];
    }
  } else if (blk < 384) { // Wc f2bf
    int i = (blk - 128) * 256 + tid;
    float4 v = ((const float4*)Wc)[i];
    bf16x4 o;
    o[0] = (__bf16)v.x; o[1] = (__bf16)v.y; o[2] = (__bf16)v.z; o[3] = (__bf16)v.w;
    *(bf16x4*)(wcb + 4L * i) = o;
  } else if (blk < 2432) { // genT
    int i = blk - 384;
    for (int d = tid; d < 512; d += 256) {
      float v = (i < 2047) ? gen[(long)d * 2047 + i] : 0.f;
      genT[(long)i * 512 + d] = (__bf16)v;
    }
  } else if (blk < 10624) { // x f2bf
    int i = (blk - 2432) * 256 + tid;
    float4 v = ((const float4*)x)[i];
    bf16x4 o;
    o[0] = (__bf16)v.x; o[1] = (__bf16)v.y; o[2] = (__bf16)v.z; o[3] = (__bf16)v.w;
    *(bf16x4*)(xb + 4L * i) = o;
  } else { // g2t partials
    int t = blk - 10624;       // 0..503
    int i = t % 63, c = t / 63;
    int d0 = c * 64, k = tid;
    float a0 = 0.f, a1 = 0.f;
#pragma unroll 8
    for (int u = 0; u < 64; ++u) {
      int d = d0 + u;
      float g = gen[(long)d * 2047 + 992 + i];
      a0 += Wq[(long)d * 512 + k] * g;
      a1 += Wq[(long)d * 512 + k + 256] * g;
    }
    long o = ((long)c * 63 + i) * 512;
    gp[o + k] = a0;
    gp[o + k + 256] = a1;
  }
}

// ---------------------------------------------------------------------------
// Shared 128x128 3-deep counted-vmcnt GEMM core (BK=32, 4 waves, C=A@B^T),
// LDS XOR-swizzled. 4 loads/stage -> steady wait vmcnt(8), tail 4/0.
__device__ __forceinline__ void gemm128_body(
    const __bf16* __restrict__ Ab, const __bf16* __restrict__ Bb,
    __bf16 (*As)[128 * 32], __bf16 (*Bs)[128 * 32],
    int m0, int n0, int K, int nt, f32x4 (&acc)[4][4]) {
  const int tid = threadIdx.x;
  const int w = tid >> 6, l = tid & 63;
  const int srow = w * 16 + (l >> 2);
  const int scol = (((l & 3) ^ ((l >> 3) & 3))) * 8;     // swizzled source chunk
  const int wr = (w >> 1) * 64, wc = (w & 1) * 64;
  const int fr = l & 15;
  const int cp = (((l >> 4) ^ ((fr >> 1) & 3))) << 3;    // swizzled read chunk (elems)

  auto STAGE = [&](int t, int p) {
    const int k0 = t << 5;
    gl_lds16(Ab + (long)(m0 + srow) * K + (k0 + scol),      &As[p][(w * 16) * 32]);
    gl_lds16(Ab + (long)(m0 + 64 + srow) * K + (k0 + scol), &As[p][(64 + w * 16) * 32]);
    gl_lds16(Bb + (long)(n0 + srow) * K + (k0 + scol),      &Bs[p][(w * 16) * 32]);
    gl_lds16(Bb + (long)(n0 + 64 + srow) * K + (k0 + scol), &Bs[p][(64 + w * 16) * 32]);
  };
  STAGE(0, 0);
  if (nt > 1) STAGE(1, 1);
  if (nt > 2) STAGE(2, 2);
  int p = 0;
  for (int t = 0; t < nt; ++t) {
    const int ahead = nt - 1 - t;
    if (ahead >= 2)      asm volatile("s_waitcnt vmcnt(8)\ns_barrier" ::: "memory");
    else if (ahead == 1) asm volatile("s_waitcnt vmcnt(4)\ns_barrier" ::: "memory");
    else                 asm volatile("s_waitcnt vmcnt(0)\ns_barrier" ::: "memory");
    bf16x8 af[4], bg[4];
#pragma unroll
    for (int i = 0; i < 4; ++i) af[i] = *(const bf16x8*)&As[p][(wr + i * 16 + fr) * 32 + cp];
#pragma unroll
    for (int j = 0; j < 4; ++j) bg[j] = *(const bf16x8*)&Bs[p][(wc + j * 16 + fr) * 32 + cp];
    asm volatile("s_waitcnt lgkmcnt(0)\ns_barrier" ::: "memory");
    if (t + 3 < nt) STAGE(t + 3, p);
#pragma unroll
    for (int i = 0; i < 4; ++i)
#pragma unroll
      for (int j = 0; j < 4; ++j)
        acc[i][j] = __builtin_amdgcn_mfma_f32_16x16x32_bf16(af[i], bg[j], acc[i][j], 0, 0, 0);
    p = (p == 2) ? 0 : p + 1;
  }
}

// ---------------------------------------------------------------------------
// Merged weight-folding GEMMs + g2t reduce in one dispatch (206 blocks):
//   blk [0,16):    Pmat = wcb @ wvT^T   (512x512, grid 4x4)
//   blk [16,80):   Bg   = genT @ wqT^T  (2048x512, grid 16x4)
//   blk [80,206):  g2t reduce (8 partial slabs -> f32)
__global__ __launch_bounds__(256) void gemm_fold(
    const __bf16* __restrict__ A1, const __bf16* __restrict__ B1, __bf16* __restrict__ C1,
    const __bf16* __restrict__ A2, const __bf16* __restrict__ B2, __bf16* __restrict__ C2,
    const float* __restrict__ gp, float* __restrict__ g2t) {
  __shared__ __bf16 As[3][128 * 32];
  __shared__ __bf16 Bs[3][128 * 32];
  const int b = blockIdx.x;
  if (b >= 80) { // g2t reduce
    int idx = (b - 80) * 256 + threadIdx.x;
    if (idx >= 63 * 512) return;
    float s = 0.f;
#pragma unroll
    for (int c = 0; c < 8; ++c) s += gp[(long)c * 63 * 512 + idx];
    g2t[idx] = s;
    return;
  }
  const __bf16 *Ab, *Bb; __bf16* C; int m0, n0;
  if (b < 16) { Ab = A1; Bb = B1; C = C1; m0 = (b >> 2) * 128; n0 = (b & 3) * 128; }
  else { int t = b - 16; Ab = A2; Bb = B2; C = C2; m0 = (t >> 2) * 128; n0 = (t & 3) * 128; }

  f32x4 acc[4][4] = {};
  gemm128_body(Ab, Bb, As, Bs, m0, n0, 512, 16, acc);

  const int l = threadIdx.x & 63, w = threadIdx.x >> 6;
  const int rbase = m0 + (w >> 1) * 64 + ((l >> 4) << 2);
  const int cbase = n0 + (w & 1) * 64 + (l & 15);
#pragma unroll
  for (int i = 0; i < 4; ++i)
#pragma unroll
    for (int r = 0; r < 4; ++r) {
      long row = rbase + i * 16 + r;
#pragma unroll
      for (int j = 0; j < 4; ++j) C[row * 512 + cbase + j * 16] = (__bf16)acc[i][j][r];
    }
}

// ---------------------------------------------------------------------------
// Final GEMM: OUT[b] = normalize(Wrelu[b]) @ vT[b]^T -> f32 d_out.
// TRIL: K-loop ends at m0+128. 1D XCD-chunked grid (512 = 8 x 64).
__global__ __launch_bounds__(256) void gemm_out(
    const __bf16* __restrict__ A, const __bf16* __restrict__ B, float* __restrict__ Cv,
    const float* __restrict__ aux) {
  __shared__ __bf16 As[3][128 * 32];
  __shared__ __bf16 Bs[3][128 * 32];
  int bid = blockIdx.x;
  int swz = (bid & 7) * 64 + (bid >> 3);
  int xn = swz & 3, tt = swz >> 2;
  int yn = tt & 7, bz = tt >> 3;
  const int m0 = yn * 128, n0 = xn * 128;
  const int K = 1024;
  const __bf16* Ab = A + (long)bz * 1024 * 1024;
  const __bf16* Bb = B + (long)bz * 512 * 1024;
  const int nt = (m0 + 128) >> 5;   // min(K, m0+128)/32

  f32x4 acc[4][4] = {};
  gemm128_body(Ab, Bb, As, Bs, m0, n0, K, nt, acc);

  const int l = threadIdx.x & 63, w = threadIdx.x >> 6;
  const int rbase = m0 + (w >> 1) * 64 + ((l >> 4) << 2);
  const int cbase = n0 + (w & 1) * 64 + (l & 15);
  float* C = Cv + (long)bz * 512 * 1024;
  const float* ax = aux + bz * 1024;
#pragma unroll
  for (int i = 0; i < 4; ++i)
#pragma unroll
    for (int r = 0; r < 4; ++r) {
      long row = rbase + i * 16 + r;
      float sc = 1.f / (ax[row] + 1e-8f);
#pragma unroll
      for (int j = 0; j < 4; ++j) C[row * 512 + cbase + j * 16] = acc[i][j][r] * sc;
    }
}

// ---------------------------------------------------------------------------
// Merged x-GEMM, BM=256 x BN=128, 512 threads / 8 waves, BK=32, 3-deep
// counted-vmcnt (3 loads/stage -> steady vmcnt(6)), LDS XOR-swizzled.
// Per m-tile y (256 rows): 14 n-tiles:
//   xt in [0,10):  band vs Bg, n0 = (6 - 2*(y&3) + xt)*128
//                  -> gathered S[row][jj], jj = col-1023+(row&1023)
//   xt in [10,14): vT vs Pmat -> vT[(row>>10)*512 + col][row&1023]
// XCD-swizzled linear grid: 896 = 8 * 112 blocks.
__global__ __launch_bounds__(512) void gemm_x(
    const __bf16* __restrict__ A, const __bf16* __restrict__ Bg,
    const __bf16* __restrict__ Pm, __bf16* __restrict__ S, __bf16* __restrict__ vT) {
  __shared__ __bf16 As[3][256 * 32];
  __shared__ __bf16 Bs[3][128 * 32];
  const int tid = threadIdx.x;
  const int w = tid >> 6, l = tid & 63;

  int wgid = blockIdx.x;
  int swz = (wgid & 7) * 112 + (wgid >> 3);
  int y = swz / 14, xt = swz - y * 14;
  const bool band = (xt < 10);
  const int m0 = y * 256;
  const int n0 = band ? (6 - 2 * (y & 3) + xt) * 128 : (xt - 10) * 128;
  const __bf16* Bb = band ? Bg : Pm;
  const int K = 512;

  const int srow = w * 16 + (l >> 2);
  const int scol = (((l & 3) ^ ((l >> 3) & 3))) * 8;    // swizzled source chunk
  const int wr = (w >> 1) * 64;
  const int wc = (w & 1) * 64;
  const int fr = l & 15;
  const int cp = (((l >> 4) ^ ((fr >> 1) & 3))) << 3;   // swizzled read chunk (elems)

  f32x4 acc[4][4] = {};

  auto STAGE = [&](int t, int p) {
    const int k0 = t << 5;
    gl_lds16(A + (long)(m0 + srow) * K + (k0 + scol),        &As[p][(w * 16) * 32]);
    gl_lds16(A + (long)(m0 + 128 + srow) * K + (k0 + scol),  &As[p][(128 + w * 16) * 32]);
    gl_lds16(Bb + (long)(n0 + srow) * K + (k0 + scol),       &Bs[p][(w * 16) * 32]);
  };

  STAGE(0, 0);
  STAGE(1, 1);
  STAGE(2, 2);

  int p = 0;
  for (int t = 0; t < 16; ++t) {
    const int ahead = 15 - t;
    if (ahead >= 2)      asm volatile("s_waitcnt vmcnt(6)\ns_barrier" ::: "memory");
    else if (ahead == 1) asm volatile("s_waitcnt vmcnt(3)\ns_barrier" ::: "memory");
    else                 asm volatile("s_waitcnt vmcnt(0)\ns_barrier" ::: "memory");
    bf16x8 af[4], bg[4];
#pragma unroll
    for (int i = 0; i < 4; ++i) af[i] = *(const bf16x8*)&As[p][(wr + i * 16 + fr) * 32 + cp];
#pragma unroll
    for (int j = 0; j < 4; ++j) bg[j] = *(const bf16x8*)&Bs[p][(wc + j * 16 + fr) * 32 + cp];
    asm volatile("s_waitcnt lgkmcnt(0)\ns_barrier" ::: "memory");
    if (t + 3 < 16) STAGE(t + 3, p);
#pragma unroll
    for (int i = 0; i < 4; ++i)
#pragma unroll
      for (int j = 0; j < 4; ++j)
        acc[i][j] = __builtin_amdgcn_mfma_f32_16x16x32_bf16(af[i], bg[j], acc[i][j], 0, 0, 0);
    p = (p == 2) ? 0 : p + 1;
  }

  const int rbase = m0 + wr + ((l >> 4) << 2);
  const int cbase = n0 + wc + fr;

  if (band) {
#pragma unroll
    for (int i = 0; i < 4; ++i)
#pragma unroll
      for (int r = 0; r < 4; ++r) {
        int row = rbase + i * 16 + r;
        int lloc = row & 1023;
#pragma unroll
        for (int j = 0; j < 4; ++j) {
          int jj = cbase + j * 16 - 1023 + lloc;
          if ((unsigned)jj < 1024u)
            S[(long)row * 1024 + jj] = (__bf16)acc[i][j][r];
        }
      }
  } else {
#pragma unroll
    for (int i = 0; i < 4; ++i) {
      int gm = rbase + i * 16;
      int bt = gm >> 10, lloc = gm & 1023;
#pragma unroll
      for (int j = 0; j < 4; ++j) {
        bf16x4 pk;
        pk[0] = (__bf16)acc[i][j][0]; pk[1] = (__bf16)acc[i][j][1];
        pk[2] = (__bf16)acc[i][j][2]; pk[3] = (__bf16)acc[i][j][3];
        *(bf16x4*)&vT[((long)bt * 512 + cbase + j * 16) * 1024 + lloc] = pk;
      }
    }
  }
}

// ---------------------------------------------------------------------------
// Cumsum over l of S[b,l,j], 64 chunks of 16 rows, bf16x8-vectorized.
// Blocks with c<8 also zero the rowsum segment (replaces the memset dispatch).
__global__ __launch_bounds__(128) void chunk_sums(const __bf16* __restrict__ S,
                                                  float* __restrict__ csum,
                                                  float* __restrict__ rowsum) {
  int j0 = threadIdx.x * 8;
  int c = blockIdx.x, b = blockIdx.y;
  if (c < 8) rowsum[b * 1024 + c * 128 + threadIdx.x] = 0.f;
  const __bf16* Sb = S + (long)b * 1024 * 1024;
  float a[8] = {};
  int l0 = c * 16;
  for (int l = l0; l < l0 + 16; ++l) {
    bf16x8 v = *(const bf16x8*)&Sb[(long)l * 1024 + j0];
#pragma unroll
    for (int k = 0; k < 8; ++k) a[k] += (float)v[k];
  }
  long o = ((long)(b * 64 + c) << 10) + j0;
#pragma unroll
  for (int k = 0; k < 8; ++k) csum[o + k] = a[k];
}

// ---------------------------------------------------------------------------
// Merged: blocks [0,64) = exclusive scan (parallel-load, register array);
//         blocks [64,4160) = small_dots (exact f32 path, rows l<32 -> Sbuf).
__global__ __launch_bounds__(256) void scan_dots(
    float* __restrict__ csum,
    const float* __restrict__ x, const float* __restrict__ g2t, float* __restrict__ Sg) {
  const int blk = blockIdx.x, tid = threadIdx.x;
  if (blk < 64) {
    int idx = blk * 256 + tid; // 0..16383
    int b = idx >> 10, j = idx & 1023;
    long base = ((long)b * 64 << 10) + j;
    float v[64];
#pragma unroll
    for (int c = 0; c < 64; ++c) v[c] = csum[base + ((long)c << 10)];
    float s = 0.f;
#pragma unroll
    for (int c = 0; c < 64; ++c) { csum[base + ((long)c << 10)] = s; s += v[c]; }
  } else {
    int gid = (blk - 64) * 4 + (tid >> 6); // 0..16383
    int lane = tid & 63;
    int b = gid >> 10, rem = gid & 1023, m = rem >> 5, j = rem & 31;
    const float4* xr = (const float4*)(x + ((long)b * 1024 + m) * 512);
    const float4* gr = (const float4*)(g2t + (long)(31 - m + j) * 512);
    float4 a0 = xr[lane * 2], a1 = xr[lane * 2 + 1];
    float4 c0 = gr[lane * 2], c1 = gr[lane * 2 + 1];
    float s = a0.x * c0.x + a0.y * c0.y + a0.z * c0.z + a0.w * c0.w
            + a1.x * c1.x + a1.y * c1.y + a1.z * c1.z + a1.w * c1.w;
#pragma unroll
    for (int off = 32; off; off >>= 1) s += __shfl_down(s, off);
    if (lane == 0) Sg[gid] = s;
  }
}

// ---------------------------------------------------------------------------
// Walk chunk with offset, relu+tril, bf16x8 store (skip dead tiles), fused
// rowsum atomics. EXACT PATH: blocks c<2, threads j0<32 use Sbuf (f32 dots)
// instead of Smat -> rows l<32 get exact weights AND exact rowsum.
__global__ __launch_bounds__(128) void cumsum_relu(const __bf16* __restrict__ S,
                                                   const float* __restrict__ csum,
                                                   const float* __restrict__ Sx,
                                                   __bf16* __restrict__ wrelu,
                                                   float* __restrict__ rowsum) {
  int j0 = threadIdx.x * 8;
  int c = blockIdx.x, b = blockIdx.y;
  const bool exact = (c < 2) && (j0 < 32);
  float run[8];
  if (exact) {
#pragma unroll
    for (int k = 0; k < 8; ++k) run[k] = 0.f;
    for (int m = 0; m < c * 16; ++m)
#pragma unroll
      for (int k = 0; k < 8; ++k) run[k] += Sx[b * 1024 + m * 32 + j0 + k];
  } else {
    long co = ((long)(b * 64 + c) << 10) + j0;
#pragma unroll
    for (int k = 0; k < 8; ++k) run[k] = csum[co + k];
  }
  const __bf16* Sb = S + (long)b * 1024 * 1024;
  __bf16* wr = wrelu + (long)b * 1024 * 1024;
  int l0 = c * 16;
  for (int l = l0; l < l0 + 16; ++l) {
    bf16x8 o;
    float rs = 0.f;
    if (exact) {
#pragma unroll
      for (int k = 0; k < 8; ++k) {
        run[k] += Sx[b * 1024 + l * 32 + j0 + k];
        float val = (j0 + k <= l) ? fmaxf(run[k], 0.f) : 0.f;
        o[k] = (__bf16)val;
        rs += val;
      }
    } else {
      bf16x8 v = *(const bf16x8*)&Sb[(long)l * 1024 + j0];
#pragma unroll
      for (int k = 0; k < 8; ++k) {
        run[k] += (float)v[k];
        float val = (j0 + k <= l) ? fmaxf(run[k], 0.f) : 0.f;
        o[k] = (__bf16)val;
        rs += val;
      }
    }
    if (j0 < (((l >> 7) + 1) << 7))
      *(bf16x8*)&wr[(long)l * 1024 + j0] = o;
#pragma unroll
    for (int off = 32; off; off >>= 1) rs += __shfl_down(rs, off);
    if ((threadIdx.x & 63) == 0 && rs != 0.f) atomicAdd(&rowsum[b * 1024 + l], rs);
  }
}

// ---------------------------------------------------------------------------
extern "C" void kernel_launch(void* const* d_in, const int* in_sizes, int n_in,
                              void* d_out, int out_size, void* d_ws, size_t ws_size,
                              hipStream_t stream) {
  const float* x   = (const float*)d_in[0];
  const float* gen = (const float*)d_in[1];
  const float* Wq  = (const float*)d_in[2];
  const float* Wv  = (const float*)d_in[3];
  const float* Wc  = (const float*)d_in[4];

  char* ws = (char*)d_ws;
  __bf16* xb    = (__bf16*)(ws + 0L);
  __bf16* vT    = (__bf16*)(ws + 33554432L);
  __bf16* Smat  = (__bf16*)(ws + 67108864L);   // gathered scores, 32 MiB
  __bf16* wrelu = (__bf16*)(ws + 134217728L);
  __bf16* genT  = (__bf16*)(ws + 167772160L);
  __bf16* wqT   = (__bf16*)(ws + 169869312L);
  __bf16* wvT   = (__bf16*)(ws + 170393600L);
  __bf16* wcb   = (__bf16*)(ws + 170917888L);
  float*  g2t   = (float*)(ws + 171442176L);
  // overlays in the free region at 16 MiB:
  float*  csum  = (float*)(ws + 16777216L);            // 4 MiB (16*64*1024 f32)
  float*  rsum  = (float*)(ws + 16777216L + 4194304L); // 64 KiB
  float*  Sbuf  = (float*)(ws + 16777216L + 4259840L); // 64 KiB
  // overlays in the free region at 48 MiB:
  __bf16* Pmat  = (__bf16*)(ws + 50331648L);           // 512x512 bf16 (Wc@Wv)
  __bf16* Bg    = (__bf16*)(ws + 51380224L);           // 2048x512 bf16 (gen^T@Wq^T)
  float*  gp    = (float*)(ws + 58720256L);            // 1 MiB g2t partials

  // merged prep: transposes + f2bf (Wc, x) + genT + g2t partials
  prep_kernel<<<11128, 256, 0, stream>>>(x, gen, Wq, Wv, Wc, xb, genT, wqT, wvT, wcb, gp);

  // merged weight folding (Pmat, Bg) + g2t reduce, one dispatch
  gemm_fold<<<206, 256, 0, stream>>>(wcb, wvT, Pmat, genT, wqT, Bg, gp, g2t);

  // merged: gathered S = band(x@Bg^T) ; vT = (x@P^T)^T   (256x128 tile, swizzled)
  gemm_x<<<896, 512, 0, stream>>>(xb, Bg, Pmat, Smat, vT);

  // cumsum + relu/tril + fused rowsum (64 chunks of 16; chunk_sums zeros rsum)
  chunk_sums<<<dim3(64, 16), 128, 0, stream>>>(Smat, csum, rsum);
  scan_dots<<<4160, 256, 0, stream>>>(csum, x, g2t, Sbuf);
  cumsum_relu<<<dim3(64, 16), 128, 0, stream>>>(Smat, csum, Sbuf, wrelu, rsum);

  // OUT = normalize(Wrelu) @ vc  (batched, triangular) -> f32 d_out directly
  gemm_out<<<512, 256, 0, stream>>>(wrelu, vT, (float*)d_out, rsum);
}